// Round 7
// baseline (49.530 us; speedup 1.0000x reference)
//
#include <hip/hip_runtime.h>
#include <cstdint>

// Problem constants (match reference)
#define BB 32
#define NN 32768
#define CC 21
#define K1_BLK 256
#define PPT 2                                  // priors per thread
#define TILE (K1_BLK * PPT)                    // 512
#define K1_GRID ((BB * NN) / TILE)             // 2048
#define BLKROW (NN / TILE)                     // 64 k1-blocks per row

// K2 geometry
#define K2T 1024

typedef float f4 __attribute__((ext_vector_type(4)));

// native transcendentals (1-ulp; output threshold 0.39 absolute -> huge slack)
__device__ __forceinline__ float fexp2(float x) {
    float r; asm("v_exp_f32 %0, %1" : "=v"(r) : "v"(x)); return r;
}
__device__ __forceinline__ float flog2(float x) {
    float r; asm("v_log_f32 %0, %1" : "=v"(r) : "v"(x)); return r;
}

// ---------------------------------------------------------------------------
// K1 v7: register streaming (v5 core) + per-block non-atomic level-1 hist
// (1024 bins of key bits[31:21], ushort-packed, 2 KB/block). Also resets the
// k2 completion counter each call (runs before k2 in stream order).
// ---------------------------------------------------------------------------
__global__ __launch_bounds__(K1_BLK) void k1_compute(
    const float* __restrict__ conf, const float* __restrict__ pred,
    const int* __restrict__ labels, const float* __restrict__ gt,
    unsigned* __restrict__ keys, float* __restrict__ pce,
    float* __restrict__ psl1, int* __restrict__ pcnt,
    unsigned short* __restrict__ bhist, unsigned* __restrict__ done)
{
    __shared__ unsigned h4[4096];              // 16 KB: 1024 bins x 4 copies
    __shared__ float wce[4], wsl[4];
    __shared__ int   wcnt[4];

    const int tid = threadIdx.x;
    const int lane = tid & 63;
    const int wid = tid >> 6;
    const size_t p0 = (size_t)blockIdx.x * TILE + tid;
    const size_t p1 = p0 + K1_BLK;

    if (blockIdx.x == 0 && tid == 0) *done = 0u;   // k2's counter starts clean

#pragma unroll
    for (int i = 0; i < 16; ++i) h4[tid + i * K1_BLK] = 0;

    // ---- issue ALL loads up front, nothing consumed yet
    const int lab0 = labels[p0];
    const int lab1 = labels[p1];
    const float* cp0 = conf + p0 * CC;
    const float* cp1 = conf + p1 * CC;
    f4 A0, A1, A2, A3, A4, B0, B1, B2, B3, B4;
    __builtin_memcpy(&A0, cp0 +  0, 16);
    __builtin_memcpy(&A1, cp0 +  4, 16);
    __builtin_memcpy(&A2, cp0 +  8, 16);
    __builtin_memcpy(&A3, cp0 + 12, 16);
    __builtin_memcpy(&A4, cp0 + 16, 16);
    __builtin_memcpy(&B0, cp1 +  0, 16);
    __builtin_memcpy(&B1, cp1 +  4, 16);
    __builtin_memcpy(&B2, cp1 +  8, 16);
    __builtin_memcpy(&B3, cp1 + 12, 16);
    __builtin_memcpy(&B4, cp1 + 16, 16);
    const float a20 = cp0[20];
    const float b20 = cp1[20];

    const bool pos0 = lab0 > 0;
    const bool pos1 = lab1 > 0;

    // sparse (~3%) SmoothL1 for both priors
    float sl = 0.f;
    if (pos0) {
        const float* pp = pred + p0 * 5;
        const float* gg = gt + p0 * 5;
#pragma unroll
        for (int j = 0; j < 5; ++j) {
            float d = fabsf(pp[j] - gg[j]);
            sl += (d < 1.f) ? 0.5f * d * d : (d - 0.5f);
        }
    }
    if (pos1) {
        const float* pp = pred + p1 * 5;
        const float* gg = gt + p1 * 5;
#pragma unroll
        for (int j = 0; j < 5; ++j) {
            float d = fabsf(pp[j] - gg[j]);
            sl += (d < 1.f) ? 0.5f * d * d : (d - 0.5f);
        }
    }

    // ---- prior 0: 21-class lse + logp[lab] gather via selects
    float s0 = 0.f, cl0 = 0.f;
#define KS(Q, J, IDX, LAB, SACC, CACC) { const float v_ = Q[J]; \
        SACC += fexp2(v_ * 1.44269504f); \
        CACC = ((IDX) == (LAB)) ? v_ : CACC; }
    KS(A0,0,0,lab0,s0,cl0) KS(A0,1,1,lab0,s0,cl0) KS(A0,2,2,lab0,s0,cl0) KS(A0,3,3,lab0,s0,cl0)
    KS(A1,0,4,lab0,s0,cl0) KS(A1,1,5,lab0,s0,cl0) KS(A1,2,6,lab0,s0,cl0) KS(A1,3,7,lab0,s0,cl0)
    KS(A2,0,8,lab0,s0,cl0) KS(A2,1,9,lab0,s0,cl0) KS(A2,2,10,lab0,s0,cl0) KS(A2,3,11,lab0,s0,cl0)
    KS(A3,0,12,lab0,s0,cl0) KS(A3,1,13,lab0,s0,cl0) KS(A3,2,14,lab0,s0,cl0) KS(A3,3,15,lab0,s0,cl0)
    KS(A4,0,16,lab0,s0,cl0) KS(A4,1,17,lab0,s0,cl0) KS(A4,2,18,lab0,s0,cl0) KS(A4,3,19,lab0,s0,cl0)
    { const float v_ = a20; s0 += fexp2(v_ * 1.44269504f); cl0 = (20 == lab0) ? v_ : cl0; }
    const float lse0 = 0.6931471805599453f * flog2(s0);
    const float mining0 = fmaxf(lse0 - A0[0], 0.f);
    const unsigned key0 = pos0 ? 0u : __float_as_uint(mining0);
    keys[p0] = key0;
    float ce = pos0 ? (lse0 - cl0) : 0.f;
    int cnt = pos0 ? 1 : 0;

    // ---- prior 1
    float s1 = 0.f, cl1 = 0.f;
    KS(B0,0,0,lab1,s1,cl1) KS(B0,1,1,lab1,s1,cl1) KS(B0,2,2,lab1,s1,cl1) KS(B0,3,3,lab1,s1,cl1)
    KS(B1,0,4,lab1,s1,cl1) KS(B1,1,5,lab1,s1,cl1) KS(B1,2,6,lab1,s1,cl1) KS(B1,3,7,lab1,s1,cl1)
    KS(B2,0,8,lab1,s1,cl1) KS(B2,1,9,lab1,s1,cl1) KS(B2,2,10,lab1,s1,cl1) KS(B2,3,11,lab1,s1,cl1)
    KS(B3,0,12,lab1,s1,cl1) KS(B3,1,13,lab1,s1,cl1) KS(B3,2,14,lab1,s1,cl1) KS(B3,3,15,lab1,s1,cl1)
    KS(B4,0,16,lab1,s1,cl1) KS(B4,1,17,lab1,s1,cl1) KS(B4,2,18,lab1,s1,cl1) KS(B4,3,19,lab1,s1,cl1)
    { const float v_ = b20; s1 += fexp2(v_ * 1.44269504f); cl1 = (20 == lab1) ? v_ : cl1; }
#undef KS
    const float lse1 = 0.6931471805599453f * flog2(s1);
    const float mining1 = fmaxf(lse1 - B0[0], 0.f);
    const unsigned key1 = pos1 ? 0u : __float_as_uint(mining1);
    keys[p1] = key1;
    ce += pos1 ? (lse1 - cl1) : 0.f;
    cnt += pos1 ? 1 : 0;

    // ---- deterministic block reduction (fixed trees)
#pragma unroll
    for (int d = 32; d > 0; d >>= 1) {
        ce  += __shfl_down(ce, d);
        sl  += __shfl_down(sl, d);
        cnt += __shfl_down(cnt, d);
    }
    if (lane == 0) { wce[wid] = ce; wsl[wid] = sl; wcnt[wid] = cnt; }
    __syncthreads();   // covers h4 zeroing AND wce/wsl/wcnt

    // ---- local hist of both keys' top 11 bits (finite >=0 -> bin <= 1019)
    const unsigned c4i = lane & 3;
    atomicAdd(&h4[((key0 >> 21) << 2) | c4i], 1u);
    atomicAdd(&h4[((key1 >> 21) << 2) | c4i], 1u);

    if (tid == 0) {
        float tce = 0.f, tsl = 0.f; int tc = 0;
#pragma unroll
        for (int w = 0; w < 4; ++w) { tce += wce[w]; tsl += wsl[w]; tc += wcnt[w]; }
        pce[blockIdx.x]  = tce;
        psl1[blockIdx.x] = tsl;
        pcnt[blockIdx.x] = tc;     // non-atomic per-block count
    }
    __syncthreads();   // hist complete

    // ---- flush: 4 bins/thread, packed ushorts (counts <= 512), one uint2
    const int b0 = tid << 2;
    const unsigned n0 = h4[(b0 << 2)] + h4[(b0 << 2) | 1] + h4[(b0 << 2) | 2] + h4[(b0 << 2) | 3];
    const unsigned n1 = h4[((b0 + 1) << 2)] + h4[((b0 + 1) << 2) | 1] + h4[((b0 + 1) << 2) | 2] + h4[((b0 + 1) << 2) | 3];
    const unsigned n2 = h4[((b0 + 2) << 2)] + h4[((b0 + 2) << 2) | 1] + h4[((b0 + 2) << 2) | 2] + h4[((b0 + 2) << 2) | 3];
    const unsigned n3 = h4[((b0 + 3) << 2)] + h4[((b0 + 3) << 2) | 1] + h4[((b0 + 3) << 2) | 2] + h4[((b0 + 3) << 2) | 3];
    uint2 pk;
    pk.x = n0 | (n1 << 16);
    pk.y = n2 | (n3 << 16);
    reinterpret_cast<uint2*>(bhist + (size_t)blockIdx.x * 1024)[tid] = pk;
}

// ---------------------------------------------------------------------------
// Suffix-scan over 2048 bins (2 bins/thread) + crossing pick.
// ---------------------------------------------------------------------------
template <class GET>
__device__ __forceinline__ void sscan2048(
    GET get, unsigned* ss, unsigned* swsum,
    int* s_bin, int* s_above, unsigned want, int tid, int lane, int wid)
{
    const int b0 = 2047 - 2 * tid;     // descending scan order
    const int b1 = 2046 - 2 * tid;
    const unsigned m0 = get(b0), m1 = get(b1);
    unsigned v = m0 + m1;
#pragma unroll
    for (int d = 1; d < 64; d <<= 1) {
        unsigned u = __shfl_up(v, d);
        if (lane >= d) v += u;
    }
    if (lane == 63) swsum[wid] = v;
    __syncthreads();
    if (wid == 0) {
        unsigned wv = (lane < 16) ? swsum[lane] : 0;
#pragma unroll
        for (int d = 1; d < 16; d <<= 1) {
            unsigned u = __shfl_up(wv, d);
            if (lane >= d) wv += u;
        }
        if (lane < 16) swsum[lane] = wv;
    }
    __syncthreads();
    const unsigned off = wid ? swsum[wid - 1] : 0;
    const unsigned incl = off + v;     // suffix through b1
    const unsigned sb0 = incl - m1;    // suffix through b0
    ss[b0] = sb0;
    ss[b1] = incl;
    __syncthreads();
    if (sb0 >= want && (b0 == 2047 || ss[b0 + 1] < want)) {
        *s_bin = b0; *s_above = (b0 == 2047) ? 0 : (int)ss[b0 + 1];
    }
    if (incl >= want && ss[b1 + 1] < want) {
        *s_bin = b1; *s_above = (int)ss[b1 + 1];
    }
    __syncthreads();
}

// ---------------------------------------------------------------------------
// K2 v7: level-1 counts summed from k1's per-block hists (no LDS-atomic
// build); levels 2/3 + final from register-resident keys (v6 path).
// Last finishing block performs the global reduction (deterministic fixed
// tree) and writes the two output scalars -> k3 eliminated.
// ---------------------------------------------------------------------------
__global__ __launch_bounds__(K2T) void k2_select(
    const unsigned* __restrict__ keys, const int* __restrict__ pcnt,
    const unsigned short* __restrict__ bhist,
    const float* __restrict__ pce, const float* __restrict__ psl1,
    double* __restrict__ row_sumneg, unsigned* __restrict__ done,
    float* __restrict__ out)
{
    const int b = blockIdx.x;
    const int tid = threadIdx.x;
    const int lane = tid & 63;
    const int wid = tid >> 6;
    const unsigned* rk = keys + (size_t)b * NN;

    __shared__ unsigned h1[4096];       // 16 KB: levels 2/3 (2 copies x 2048)
    __shared__ unsigned ss[2048];       // 8 KB suffix sums
    __shared__ unsigned swsum[16];
    __shared__ double sdred[16];
    __shared__ double fA[16], fB[16];
    __shared__ int fI[16];
    __shared__ int s_bin, s_above, s_last;
    __shared__ unsigned s_want;

    // ---- one coalesced read: 8 x uint4 per thread -> 32 keys in VGPRs
    uint4 kv[8];
    const uint4* rk4 = reinterpret_cast<const uint4*>(rk);
#pragma unroll
    for (int j = 0; j < 8; ++j) kv[j] = rk4[tid + j * K2T];

    // want = min(3 * row positives, NN)
    if (wid == 0) {
        int c = pcnt[b * BLKROW + lane];          // BLKROW == 64 == wave
#pragma unroll
        for (int d = 32; d > 0; d >>= 1) c += __shfl_down(c, d);
        if (lane == 0) s_want = (unsigned)((3 * c > NN) ? NN : 3 * c);
    }
    __syncthreads();
    const unsigned want = s_want;

    if (want > 0) {
        // ---- level 1: sum 64 per-block ushort hists; thread owns bin 1023-tid
        const int bn = 1023 - tid;
        const unsigned short* bh = bhist + (size_t)b * BLKROW * 1024;
        unsigned mv = 0;
#pragma unroll 8
        for (int j = 0; j < BLKROW; ++j) mv += bh[j * 1024 + bn];

        // descending suffix scan (1 bin/thread) + crossing pick
        {
            unsigned v = mv;
#pragma unroll
            for (int d = 1; d < 64; d <<= 1) {
                unsigned u = __shfl_up(v, d);
                if (lane >= d) v += u;
            }
            if (lane == 63) swsum[wid] = v;
            __syncthreads();
            if (wid == 0) {
                unsigned wv = (lane < 16) ? swsum[lane] : 0;
#pragma unroll
                for (int d = 1; d < 16; d <<= 1) {
                    unsigned u = __shfl_up(wv, d);
                    if (lane >= d) wv += u;
                }
                if (lane < 16) swsum[lane] = wv;
            }
            __syncthreads();
            const unsigned incl = (wid ? swsum[wid - 1] : 0) + v;
            ss[bn] = incl;
            __syncthreads();
            if (incl >= want && (bn == 1023 || ss[bn + 1] < want)) {
                s_bin = bn; s_above = (bn == 1023) ? 0 : (int)ss[bn + 1];
            }
            __syncthreads();
        }
        const unsigned bsel1 = (unsigned)s_bin;
        const unsigned want1 = want - (unsigned)s_above;

        // ---- level 2: bits[20:10] of in-bin keys, straight from registers
        for (int i = tid; i < 4096; i += K2T) h1[i] = 0;
        __syncthreads();
        const unsigned c2 = lane & 1;
#pragma unroll
        for (int j = 0; j < 8; ++j) {
#define L2ADD(K) if (((K) >> 21) == bsel1) \
            atomicAdd(&h1[((((K) >> 10) & 0x7FFu) << 1) | c2], 1u);
            L2ADD(kv[j].x) L2ADD(kv[j].y) L2ADD(kv[j].z) L2ADD(kv[j].w)
#undef L2ADD
        }
        __syncthreads();
        sscan2048([&](int bb2) { return h1[bb2 << 1] + h1[(bb2 << 1) | 1]; },
                  ss, swsum, &s_bin, &s_above, want1, tid, lane, wid);
        const unsigned bsel2 = (unsigned)s_bin;
        const unsigned want2 = want1 - (unsigned)s_above;

        // ---- level 3: bits[9:0] (1024 live bins; upper 1024 stay zero)
        for (int i = tid; i < 4096; i += K2T) h1[i] = 0;
        __syncthreads();
        const unsigned pref = (bsel1 << 11) | bsel2;   // key bits[31:10]
#pragma unroll
        for (int j = 0; j < 8; ++j) {
#define L3ADD(K) if (((K) >> 10) == pref) \
            atomicAdd(&h1[(((K) & 0x3FFu) << 1) | c2], 1u);
            L3ADD(kv[j].x) L3ADD(kv[j].y) L3ADD(kv[j].z) L3ADD(kv[j].w)
#undef L3ADD
        }
        __syncthreads();
        sscan2048([&](int bb2) { return h1[bb2 << 1] + h1[(bb2 << 1) | 1]; },
                  ss, swsum, &s_bin, &s_above, want2, tid, lane, wid);
        const unsigned T = (bsel1 << 21) | (bsel2 << 10) | (unsigned)s_bin;

        // ---- final: one register pass over all 32 keys
        int above = 0;
        double sel = 0.0;
#pragma unroll
        for (int j = 0; j < 8; ++j) {
#define FIN(K) if ((K) > T) { above++; sel += (double)__uint_as_float(K); }
            FIN(kv[j].x) FIN(kv[j].y) FIN(kv[j].z) FIN(kv[j].w)
#undef FIN
        }
#pragma unroll
        for (int d = 32; d > 0; d >>= 1) {
            above += __shfl_down(above, d);
            sel   += __shfl_down(sel, d);
        }
        if (lane == 0) { swsum[wid] = (unsigned)above; sdred[wid] = sel; }
        __syncthreads();
        if (tid == 0) {
            unsigned atot = 0; double stot = 0.0;
#pragma unroll
            for (int w = 0; w < 16; ++w) { atot += swsum[w]; stot += sdred[w]; }
            const int r = (int)want - (int)atot;   // # of ==T entries selected
            row_sumneg[b] = stot + (double)r * (double)__uint_as_float(T);
        }
    } else {
        if (tid == 0) row_sumneg[b] = 0.0;
    }

    // ---- completion: last block does the (deterministic) global reduction
    __threadfence();
    if (tid == 0) s_last = (atomicAdd(done, 1u) == BB - 1) ? 1 : 0;
    __syncthreads();
    if (s_last) {
        __threadfence();
        double ce = 0.0, sl = 0.0; int np = 0;
        for (int i = tid; i < K1_GRID; i += K2T) {   // 2 iterations
            ce += (double)pce[i];
            sl += (double)psl1[i];
            np += pcnt[i];
        }
#pragma unroll
        for (int d = 32; d > 0; d >>= 1) {
            ce += __shfl_down(ce, d);
            sl += __shfl_down(sl, d);
            np += __shfl_down(np, d);
        }
        if (lane == 0) { fA[wid] = ce; fB[wid] = sl; fI[wid] = np; }
        __syncthreads();
        if (tid == 0) {
            double tce = 0.0, tsl = 0.0; int tnp = 0;
#pragma unroll
            for (int w = 0; w < 16; ++w) { tce += fA[w]; tsl += fB[w]; tnp += fI[w]; }
            double ns = 0.0;
            for (int bb = 0; bb < BB; ++bb) ns += row_sumneg[bb];
            const double npos = (double)tnp;
            out[0] = (float)(tsl / npos);          // smooth_l1_loss / n_pos
            out[1] = (float)((tce + ns) / npos);   // classification_loss / n_pos
        }
    }
}

// ---------------------------------------------------------------------------
extern "C" void kernel_launch(void* const* d_in, const int* in_sizes, int n_in,
                              void* d_out, int out_size, void* d_ws, size_t ws_size,
                              hipStream_t stream)
{
    const float* conf   = (const float*)d_in[0];
    const float* pred   = (const float*)d_in[1];
    const int*   labels = (const int*)d_in[2];
    const float* gt     = (const float*)d_in[3];
    float* out = (float*)d_out;

    char* ws = (char*)d_ws;
    unsigned*       keys       = (unsigned*)ws;                   // 4 MB
    unsigned short* bhist      = (unsigned short*)(ws + 4194304); // 4 MB
    float*          pce        = (float*)(ws + 8388608);          // 8 KB
    float*          psl1       = (float*)(ws + 8396800);          // 8 KB
    int*            pcnt       = (int*)(ws + 8404992);            // 8 KB
    double*         row_sumneg = (double*)(ws + 8413184);         // 256 B
    unsigned*       done       = (unsigned*)(ws + 8413440);       // 4 B

    k1_compute<<<K1_GRID, K1_BLK, 0, stream>>>(conf, pred, labels, gt,
                                               keys, pce, psl1, pcnt,
                                               bhist, done);
    k2_select<<<BB, K2T, 0, stream>>>(keys, pcnt, bhist, pce, psl1,
                                      row_sumneg, done, out);
}

// Round 8
// 40.782 us; speedup vs baseline: 1.2145x; 1.2145x over previous
//
#include <hip/hip_runtime.h>
#include <cstdint>

// Problem constants (match reference)
#define BB 32
#define NN 32768
#define CC 21
#define K1_BLK 256
#define K1_GRID ((BB * NN) / K1_BLK)           // 4096 (1 prior/thread)
#define BLKROW (NN / K1_BLK)                   // 128 k1-blocks per row
#define WSTAGE 1536                            // floats per wave stage (6144 B)

// K2 geometry
#define K2T 1024
#define NC 16                                  // level-1 hist copies

// native transcendentals (1-ulp; output threshold 0.39 absolute -> huge slack)
__device__ __forceinline__ float fexp2(float x) {
    float r; asm("v_exp_f32 %0, %1" : "=v"(r) : "v"(x)); return r;
}
__device__ __forceinline__ float flog2(float x) {
    float r; asm("v_log_f32 %0, %1" : "=v"(r) : "v"(x)); return r;
}

// ---------------------------------------------------------------------------
// K1 v8: per-wave coalesced global->LDS staging, wave-local drain (no block
// barrier for memory). Each wave stages its 64 priors' 5376 B as 6 x 1 KB
// contiguous global_load_lds; lane then reads its 21 floats from LDS
// (stride-21 -> 2 lanes/bank, conflict-free). logp[lab] = one dynamic
// ds_read. Loads for labels issued first (vmcnt(6) suffices for lab use).
// ---------------------------------------------------------------------------
__global__ __launch_bounds__(K1_BLK) void k1_compute(
    const float* __restrict__ conf, const float* __restrict__ pred,
    const int* __restrict__ labels, const float* __restrict__ gt,
    unsigned* __restrict__ keys, float* __restrict__ pce,
    float* __restrict__ psl1, int* __restrict__ pcnt)
{
    __shared__ __align__(16) float lconf[4 * WSTAGE];   // 24 KB, wave-private
    __shared__ float wce[4], wsl[4];
    __shared__ int   wcnt[4];

    const int tid = threadIdx.x;
    const int lane = tid & 63;
    const int w = tid >> 6;
    const size_t p = (size_t)blockIdx.x * K1_BLK + tid;

    // label first: its consumer then needs only vmcnt(6), not a full drain
    const int lab = labels[p];

    // per-wave staging: wave's conf region = 64 priors x 84 B = 5376 B
    // = 336 x 16B slots -> 6 instrs (last clamped; dup lands in 768 B pad).
    const char* gsrc = (const char*)conf +
        (size_t)(blockIdx.x * K1_BLK + w * 64) * (CC * 4);
    float* ldst = lconf + w * WSTAGE;
#pragma unroll
    for (int s = 0; s < 6; ++s) {
        int slot = s * 64 + lane;
        if (s == 5) slot = (slot > 335) ? 335 : slot;
        __builtin_amdgcn_global_load_lds(
            (const __attribute__((address_space(1))) unsigned*)
                (gsrc + (size_t)slot * 16),
            (__attribute__((address_space(3))) unsigned*)(ldst + s * 256),
            16, 0, 0);
    }

    const bool pos = lab > 0;

    // sparse (~3%) SmoothL1: issue while staging is in flight
    float sl = 0.f;
    if (pos) {
        const float* pp = pred + p * 5;
        const float* gg = gt + p * 5;
        float pv[5], gv[5];
#pragma unroll
        for (int j = 0; j < 5; ++j) { pv[j] = pp[j]; gv[j] = gg[j]; }
#pragma unroll
        for (int j = 0; j < 5; ++j) {
            float d = fabsf(pv[j] - gv[j]);
            sl += (d < 1.f) ? 0.5f * d * d : (d - 0.5f);
        }
    }

    // wave-local drain of this wave's staging (NOT __syncthreads)
    asm volatile("s_waitcnt vmcnt(0)" ::: "memory");
    __builtin_amdgcn_sched_barrier(0);

    // lane's 21 floats at stride 21 (coprime 32 -> 2 lanes/bank, free)
    const float* my = ldst + lane * CC;
    float s_ = 0.f;
#pragma unroll
    for (int c = 0; c < CC; ++c) s_ += fexp2(my[c] * 1.44269504f);
    const float lse = 0.6931471805599453f * flog2(s_);

    const float c0 = my[0];
    const float clab = my[lab];    // dynamic per-lane ds_read (lab in 0..20)

    // mining = -logp0 = lse - conf0; clamp rounding-induced tiny negatives
    const float mining = fmaxf(lse - c0, 0.f);
    keys[p] = pos ? 0u : __float_as_uint(mining);

    float ce = pos ? (lse - clab) : 0.f;
    int cnt = pos ? 1 : 0;

    // deterministic block reduction (fixed trees)
#pragma unroll
    for (int d = 32; d > 0; d >>= 1) {
        ce  += __shfl_down(ce, d);
        sl  += __shfl_down(sl, d);
        cnt += __shfl_down(cnt, d);
    }
    if (lane == 0) { wce[w] = ce; wsl[w] = sl; wcnt[w] = cnt; }
    __syncthreads();
    if (tid == 0) {
        float tce = 0.f, tsl = 0.f; int tc = 0;
#pragma unroll
        for (int v = 0; v < 4; ++v) { tce += wce[v]; tsl += wsl[v]; tc += wcnt[v]; }
        pce[blockIdx.x]  = tce;
        psl1[blockIdx.x] = tsl;
        pcnt[blockIdx.x] = tc;     // non-atomic per-block count
    }
}

// ---------------------------------------------------------------------------
// Suffix-scan over 2048 bins (2 bins/thread) + crossing pick.
// ---------------------------------------------------------------------------
template <class GET>
__device__ __forceinline__ void sscan2048(
    GET get, unsigned* ss, unsigned* swsum,
    int* s_bin, int* s_above, unsigned want, int tid, int lane, int wid)
{
    const int b0 = 2047 - 2 * tid;     // descending scan order
    const int b1 = 2046 - 2 * tid;
    const unsigned m0 = get(b0), m1 = get(b1);
    unsigned v = m0 + m1;
#pragma unroll
    for (int d = 1; d < 64; d <<= 1) {
        unsigned u = __shfl_up(v, d);
        if (lane >= d) v += u;
    }
    if (lane == 63) swsum[wid] = v;
    __syncthreads();
    if (wid == 0) {
        unsigned wv = (lane < 16) ? swsum[lane] : 0;
#pragma unroll
        for (int d = 1; d < 16; d <<= 1) {
            unsigned u = __shfl_up(wv, d);
            if (lane >= d) wv += u;
        }
        if (lane < 16) swsum[lane] = wv;
    }
    __syncthreads();
    const unsigned off = wid ? swsum[wid - 1] : 0;
    const unsigned incl = off + v;     // suffix through b1
    const unsigned sb0 = incl - m1;    // suffix through b0
    ss[b0] = sb0;
    ss[b1] = incl;
    __syncthreads();
    if (sb0 >= want && (b0 == 2047 || ss[b0 + 1] < want)) {
        *s_bin = b0; *s_above = (b0 == 2047) ? 0 : (int)ss[b0 + 1];
    }
    if (incl >= want && ss[b1 + 1] < want) {
        *s_bin = b1; *s_above = (int)ss[b1 + 1];
    }
    __syncthreads();
}

// ---------------------------------------------------------------------------
// K2 v6 (R6 best, unchanged except BLKROW=128 want-reduce): fully
// register-resident exact top-k sum. sum = Σ(key>T) + r·T.
// ---------------------------------------------------------------------------
__global__ __launch_bounds__(K2T) void k2_select(
    const unsigned* __restrict__ keys, const int* __restrict__ pcnt,
    double* __restrict__ row_sumneg)
{
    const int b = blockIdx.x;
    const int tid = threadIdx.x;
    const int lane = tid & 63;
    const int wid = tid >> 6;
    const unsigned* rk = keys + (size_t)b * NN;

    __shared__ unsigned h1[1024 * NC];  // 64 KB (reused for levels 2/3)
    __shared__ unsigned ss[2048];       // 8 KB suffix sums
    __shared__ unsigned swsum[16];
    __shared__ double sdred[16];
    __shared__ int s_bin, s_above;
    __shared__ unsigned s_want;

    // ---- one coalesced read: 8 x uint4 per thread -> 32 keys in VGPRs
    uint4 kv[8];
    const uint4* rk4 = reinterpret_cast<const uint4*>(rk);
#pragma unroll
    for (int j = 0; j < 8; ++j) kv[j] = rk4[tid + j * K2T];

    // want = min(3 * row positives, NN); 128 per-block counts per row
    if (wid == 0) {
        int c = pcnt[b * BLKROW + lane] + pcnt[b * BLKROW + 64 + lane];
#pragma unroll
        for (int d = 32; d > 0; d >>= 1) c += __shfl_down(c, d);
        if (lane == 0) s_want = (unsigned)((3 * c > NN) ? NN : 3 * c);
    }
    for (int i = tid; i < 1024 * NC; i += K2T) h1[i] = 0;
    __syncthreads();
    const unsigned want = s_want;
    if (want == 0) { if (tid == 0) row_sumneg[b] = 0.0; return; }

    // ---- level 1: 1024-bin hist of bits[31:21] (finite >=0 -> bin <= 1019)
    const unsigned cp = lane & (NC - 1);
#pragma unroll
    for (int j = 0; j < 8; ++j) {
        atomicAdd(&h1[((kv[j].x >> 21) << 4) | cp], 1u);
        atomicAdd(&h1[((kv[j].y >> 21) << 4) | cp], 1u);
        atomicAdd(&h1[((kv[j].z >> 21) << 4) | cp], 1u);
        atomicAdd(&h1[((kv[j].w >> 21) << 4) | cp], 1u);
    }
    __syncthreads();

    // ---- level-1 scan: one bin/thread, descending suffix sums
    {
        const int bn = 1023 - tid;
        unsigned mv = 0;
#pragma unroll
        for (int c = 0; c < NC; ++c) mv += h1[(bn << 4) | c];
        unsigned v = mv;
#pragma unroll
        for (int d = 1; d < 64; d <<= 1) {
            unsigned u = __shfl_up(v, d);
            if (lane >= d) v += u;
        }
        if (lane == 63) swsum[wid] = v;
        __syncthreads();
        if (wid == 0) {
            unsigned wv = (lane < 16) ? swsum[lane] : 0;
#pragma unroll
            for (int d = 1; d < 16; d <<= 1) {
                unsigned u = __shfl_up(wv, d);
                if (lane >= d) wv += u;
            }
            if (lane < 16) swsum[lane] = wv;
        }
        __syncthreads();
        const unsigned incl = (wid ? swsum[wid - 1] : 0) + v;
        ss[bn] = incl;
        __syncthreads();
        if (incl >= want && (bn == 1023 || ss[bn + 1] < want)) {
            s_bin = bn; s_above = (bn == 1023) ? 0 : (int)ss[bn + 1];
        }
        __syncthreads();
    }
    const unsigned bsel1 = (unsigned)s_bin;
    const unsigned want1 = want - (unsigned)s_above;

    // ---- level 2: bits[20:10] of in-bin keys, straight from registers
    for (int i = tid; i < 4096; i += K2T) h1[i] = 0;
    __syncthreads();
    const unsigned c2 = lane & 1;
#pragma unroll
    for (int j = 0; j < 8; ++j) {
#define L2ADD(K) if (((K) >> 21) == bsel1) \
        atomicAdd(&h1[((((K) >> 10) & 0x7FFu) << 1) | c2], 1u);
        L2ADD(kv[j].x) L2ADD(kv[j].y) L2ADD(kv[j].z) L2ADD(kv[j].w)
#undef L2ADD
    }
    __syncthreads();
    sscan2048([&](int bn) { return h1[bn << 1] + h1[(bn << 1) | 1]; },
              ss, swsum, &s_bin, &s_above, want1, tid, lane, wid);
    const unsigned bsel2 = (unsigned)s_bin;
    const unsigned want2 = want1 - (unsigned)s_above;

    // ---- level 3: bits[9:0] (1024 live bins; upper 1024 stay zero)
    for (int i = tid; i < 4096; i += K2T) h1[i] = 0;
    __syncthreads();
    const unsigned pref = (bsel1 << 11) | bsel2;   // key bits[31:10]
#pragma unroll
    for (int j = 0; j < 8; ++j) {
#define L3ADD(K) if (((K) >> 10) == pref) \
        atomicAdd(&h1[(((K) & 0x3FFu) << 1) | c2], 1u);
        L3ADD(kv[j].x) L3ADD(kv[j].y) L3ADD(kv[j].z) L3ADD(kv[j].w)
#undef L3ADD
    }
    __syncthreads();
    sscan2048([&](int bn) { return h1[bn << 1] + h1[(bn << 1) | 1]; },
              ss, swsum, &s_bin, &s_above, want2, tid, lane, wid);
    const unsigned T = (bsel1 << 21) | (bsel2 << 10) | (unsigned)s_bin;

    // ---- final: one register pass over all 32 keys
    int above = 0;
    double sel = 0.0;
#pragma unroll
    for (int j = 0; j < 8; ++j) {
#define FIN(K) if ((K) > T) { above++; sel += (double)__uint_as_float(K); }
        FIN(kv[j].x) FIN(kv[j].y) FIN(kv[j].z) FIN(kv[j].w)
#undef FIN
    }
#pragma unroll
    for (int d = 32; d > 0; d >>= 1) {
        above += __shfl_down(above, d);
        sel   += __shfl_down(sel, d);
    }
    if (lane == 0) { swsum[wid] = (unsigned)above; sdred[wid] = sel; }
    __syncthreads();
    if (tid == 0) {
        unsigned atot = 0; double stot = 0.0;
#pragma unroll
        for (int w = 0; w < 16; ++w) { atot += swsum[w]; stot += sdred[w]; }
        const int r = (int)want - (int)atot;   // # of ==T entries selected
        row_sumneg[b] = stot + (double)r * (double)__uint_as_float(T);
    }
}

// ---------------------------------------------------------------------------
// K3: deterministic final reduction -> two scalars.
// ---------------------------------------------------------------------------
__global__ __launch_bounds__(256) void k3_final(
    const float* __restrict__ pce, const float* __restrict__ psl1,
    const int* __restrict__ pcnt, const double* __restrict__ row_sumneg,
    float* __restrict__ out)
{
    __shared__ double a[256], c[256];
    __shared__ int ic[256];
    const int tid = threadIdx.x;
    double ce = 0.0, sl = 0.0; int np = 0;
    for (int i = tid; i < K1_GRID; i += 256) {
        ce += (double)pce[i];
        sl += (double)psl1[i];
        np += pcnt[i];
    }
    a[tid] = ce; c[tid] = sl; ic[tid] = np;
    __syncthreads();
    for (int st = 128; st > 0; st >>= 1) {
        if (tid < st) {
            a[tid] += a[tid + st];
            c[tid] += c[tid + st];
            ic[tid] += ic[tid + st];
        }
        __syncthreads();
    }
    if (tid == 0) {
        double ns = 0.0;
        for (int bb = 0; bb < BB; ++bb) ns += row_sumneg[bb];
        const double npos = (double)ic[0];
        out[0] = (float)(c[0] / npos);          // smooth_l1_loss / n_pos
        out[1] = (float)((a[0] + ns) / npos);   // classification_loss / n_pos
    }
}

// ---------------------------------------------------------------------------
extern "C" void kernel_launch(void* const* d_in, const int* in_sizes, int n_in,
                              void* d_out, int out_size, void* d_ws, size_t ws_size,
                              hipStream_t stream)
{
    const float* conf   = (const float*)d_in[0];
    const float* pred   = (const float*)d_in[1];
    const int*   labels = (const int*)d_in[2];
    const float* gt     = (const float*)d_in[3];
    float* out = (float*)d_out;

    char* ws = (char*)d_ws;
    unsigned* keys       = (unsigned*)ws;                      // 4 MB
    float*    pce        = (float*)(ws + 4194304);             // 16 KB
    float*    psl1       = (float*)(ws + 4210688);             // 16 KB
    int*      pcnt       = (int*)(ws + 4227072);               // 16 KB
    double*   row_sumneg = (double*)(ws + 4243456);            // 256 B

    k1_compute<<<K1_GRID, K1_BLK, 0, stream>>>(conf, pred, labels, gt,
                                               keys, pce, psl1, pcnt);
    k2_select<<<BB, K2T, 0, stream>>>(keys, pcnt, row_sumneg);
    k3_final<<<1, 256, 0, stream>>>(pce, psl1, pcnt, row_sumneg, out);
}